// Round 6
// baseline (93.192 us; speedup 1.0000x reference)
//
#include <hip/hip_runtime.h>

#define BLOCK 256
#define DD 64
#define JJ 16

__device__ __forceinline__ float f4c(const float4& v, int i) {
    return i == 0 ? v.x : i == 1 ? v.y : i == 2 ? v.z : v.w;
}

// One row per thread, but x is staged through LDS so GLOBAL loads are
// per-instruction coalesced (8 full 128B lines per instr, each line fetched
// once -> no L1-reuse dependence, L2 traffic = 1x ideal). Wave-local
// transpose: wave stages its 64 half-rows (8KB), lane then reads its own row
// from LDS. XOR-swizzle col^= (row&7) makes both the strided reads
// conflict-free. W stays in scalar registers via uniform s_load (no LDS).
__global__ void net_circuit_kernel(
    const float* __restrict__ x, const float* __restrict__ Ws,
    const float* __restrict__ bs, float* __restrict__ out, int B)
{
    __shared__ float4 xlds[4 * 64 * 8];   // 4 waves x 64 rows x 8 float4 = 32 KB

    const int tid  = threadIdx.x;
    const int lane = tid & 63;
    const int wid  = tid >> 6;
    const long long wave_base = (long long)blockIdx.x * BLOCK + wid * 64;
    const bool full = (wave_base + 64 <= (long long)B);

    float4* __restrict__ wsl = xlds + wid * (64 * 8);
    const float4* __restrict__ x4  = reinterpret_cast<const float4*>(x);
    const float4* __restrict__ Ws4 = reinterpret_cast<const float4*>(Ws); // Ws4[n*64+d]
    const float4* __restrict__ bs4 = reinterpret_cast<const float4*>(bs);

    const int rsub = lane >> 3;   // staging: which row-octet this lane covers
    const int c8   = lane & 7;    // staging: col within the half-row

    float acc[JJ];
    #pragma unroll
    for (int j = 0; j < JJ; ++j) acc[j] = 0.0f;

    #pragma unroll
    for (int hf = 0; hf < 2; ++hf) {
        // ---- stage 64 half-rows, perfectly coalesced ----
        // instr `it`: lanes cover rows it*8..it*8+7 fully (8 x 128B lines)
        #pragma unroll
        for (int it = 0; it < 8; ++it) {
            const int r = it * 8 + rsub;          // 0..63
            const long long grow = wave_base + r;
            float4 v = make_float4(0.f, 0.f, 0.f, 0.f);
            if (full || grow < (long long)B)
                v = x4[grow * (DD / 4) + hf * 8 + c8];
            wsl[r * 8 + (c8 ^ (r & 7))] = v;      // swizzled store
        }
        __syncthreads();

        // ---- each lane consumes its own row from LDS ----
        #pragma unroll
        for (int c = 0; c < 8; ++c) {
            const float4 xv = wsl[lane * 8 + (c ^ (lane & 7))];  // conflict-free
            #pragma unroll
            for (int qq = 0; qq < 4; ++qq) {
                const int d = hf * 32 + c * 4 + qq;
                const float xs = f4c(xv, qq);
                #pragma unroll
                for (int n = 0; n < 4; ++n) {
                    const float4 w = Ws4[n * DD + d];   // uniform -> s_load_dwordx4
                    acc[n * 4 + 0] = fmaf(xs, w.x, acc[n * 4 + 0]);
                    acc[n * 4 + 1] = fmaf(xs, w.y, acc[n * 4 + 1]);
                    acc[n * 4 + 2] = fmaf(xs, w.z, acc[n * 4 + 2]);
                    acc[n * 4 + 3] = fmaf(xs, w.w, acc[n * 4 + 3]);
                }
            }
        }
        __syncthreads();   // slice reused for hf=1
    }

    float h[JJ];
    #pragma unroll
    for (int n = 0; n < 4; ++n) {
        const float4 b4 = bs4[n];   // uniform
        #pragma unroll
        for (int k = 0; k < 4; ++k) {
            const float z = acc[n * 4 + k] + f4c(b4, k);
            h[n * 4 + k] = 1.0f / (1.0f + __expf(-z));
        }
    }

    // f(17)=f(18)=1; i=16..1: neg_i=(i==3||i==7)?1:1-h[i-1]; f(i)=h*f(i+1)+neg*f(i+2)
    float f1 = 1.0f, f2 = 1.0f;
    #pragma unroll
    for (int i = JJ; i >= 1; --i) {
        const float hj = h[i - 1];
        const float neg = (i == 3 || i == 7) ? 1.0f : (1.0f - hj);
        const float fi = fmaf(hj, f1, neg * f2);
        f2 = f1;
        f1 = fi;
    }

    const long long orow = wave_base + lane;
    if (full || orow < (long long)B) out[orow] = f1;
}

extern "C" void kernel_launch(void* const* d_in, const int* in_sizes, int n_in,
                              void* d_out, int out_size, void* d_ws, size_t ws_size,
                              hipStream_t stream) {
    const float* x  = (const float*)d_in[0];
    const float* Ws = (const float*)d_in[1];
    const float* bs = (const float*)d_in[2];
    float* out = (float*)d_out;

    const int B = in_sizes[0] / DD;
    const int grid = (B + BLOCK - 1) / BLOCK;

    net_circuit_kernel<<<grid, BLOCK, 0, stream>>>(x, Ws, bs, out, B);
}

// Round 7
// 58.332 us; speedup vs baseline: 1.5976x; 1.5976x over previous
//
#include <hip/hip_runtime.h>

#define BLOCK 256
#define DD 64
#define JJ 16

__device__ __forceinline__ float f4c(const float4& v, int i) {
    return i == 0 ? v.x : i == 1 ? v.y : i == 2 ? v.z : v.w;
}

// One row per thread; x staged through a WAVE-PRIVATE LDS slice with a
// wave-local transpose. No __syncthreads anywhere: the only cross-lane dep is
// within the wave (lockstep), so a s_waitcnt lgkmcnt(0) orders write->read.
// Global loads are per-instruction coalesced (8 full 128B lines per instr,
// each line fetched exactly once -> no L1/MSHR-merge dependence, ~1x L2
// traffic). W/bias are threadIdx-uniform -> scalar s_load (K$, no VGPR cost).
// hf=1 global loads issue before hf=0 compute so HBM latency hides under FMAs.
__global__ void net_circuit_kernel(
    const float* __restrict__ x, const float* __restrict__ Ws,
    const float* __restrict__ bs, float* __restrict__ out, int B)
{
    __shared__ float4 xlds[4 * 64 * 8];   // 4 waves x (64 rows x 8 float4) = 32 KB

    const int tid  = threadIdx.x;
    const int lane = tid & 63;
    const int wid  = tid >> 6;
    const long long wave_base = (long long)blockIdx.x * BLOCK + wid * 64;
    const bool full = (wave_base + 64 <= (long long)B);

    float4* __restrict__ wsl = xlds + wid * (64 * 8);
    const float4* __restrict__ x4  = reinterpret_cast<const float4*>(x);
    const float4* __restrict__ Ws4 = reinterpret_cast<const float4*>(Ws); // Ws4[n*64+d]
    const float4* __restrict__ bs4 = reinterpret_cast<const float4*>(bs);

    const int rsub = lane >> 3;   // staging: row-within-octet this lane covers
    const int c8   = lane & 7;    // staging: float4-col within the half-row

    float acc[JJ];
    #pragma unroll
    for (int j = 0; j < JJ; ++j) acc[j] = 0.0f;

    // ---- issue hf=0 loads ----
    float4 buf[8];
    #pragma unroll
    for (int it = 0; it < 8; ++it) {
        const int r = it * 8 + rsub;
        const long long grow = wave_base + r;
        buf[it] = make_float4(0.f, 0.f, 0.f, 0.f);
        if (full || grow < (long long)B)
            buf[it] = x4[grow * (DD / 4) + 0 * 8 + c8];
    }
    // ---- write hf=0 slice (swizzled: col c stored at c^(row&7)) ----
    #pragma unroll
    for (int it = 0; it < 8; ++it) {
        const int r = it * 8 + rsub;
        wsl[r * 8 + (c8 ^ rsub)] = buf[it];
    }
    // ---- issue hf=1 loads (hide under hf=0 compute) ----
    float4 buf2[8];
    #pragma unroll
    for (int it = 0; it < 8; ++it) {
        const int r = it * 8 + rsub;
        const long long grow = wave_base + r;
        buf2[it] = make_float4(0.f, 0.f, 0.f, 0.f);
        if (full || grow < (long long)B)
            buf2[it] = x4[grow * (DD / 4) + 1 * 8 + c8];
    }

    asm volatile("s_waitcnt lgkmcnt(0)" ::: "memory");   // ds writes visible wave-wide

    // ---- hf=0 compute: lane reads its own row (2-way banks = free) ----
    #pragma unroll
    for (int c = 0; c < 8; ++c) {
        const float4 xv = wsl[lane * 8 + (c ^ (lane & 7))];
        #pragma unroll
        for (int qq = 0; qq < 4; ++qq) {
            const int d = c * 4 + qq;
            const float xs = f4c(xv, qq);
            #pragma unroll
            for (int n = 0; n < 4; ++n) {
                const float4 w = Ws4[n * DD + d];   // uniform -> s_load
                acc[n * 4 + 0] = fmaf(xs, w.x, acc[n * 4 + 0]);
                acc[n * 4 + 1] = fmaf(xs, w.y, acc[n * 4 + 1]);
                acc[n * 4 + 2] = fmaf(xs, w.z, acc[n * 4 + 2]);
                acc[n * 4 + 3] = fmaf(xs, w.w, acc[n * 4 + 3]);
            }
        }
    }

    // ---- write hf=1 slice (HW LDS unit is in-order per wave: WAR-safe) ----
    #pragma unroll
    for (int it = 0; it < 8; ++it) {
        const int r = it * 8 + rsub;
        wsl[r * 8 + (c8 ^ rsub)] = buf2[it];
    }
    asm volatile("s_waitcnt lgkmcnt(0)" ::: "memory");

    // ---- hf=1 compute ----
    #pragma unroll
    for (int c = 0; c < 8; ++c) {
        const float4 xv = wsl[lane * 8 + (c ^ (lane & 7))];
        #pragma unroll
        for (int qq = 0; qq < 4; ++qq) {
            const int d = 32 + c * 4 + qq;
            const float xs = f4c(xv, qq);
            #pragma unroll
            for (int n = 0; n < 4; ++n) {
                const float4 w = Ws4[n * DD + d];
                acc[n * 4 + 0] = fmaf(xs, w.x, acc[n * 4 + 0]);
                acc[n * 4 + 1] = fmaf(xs, w.y, acc[n * 4 + 1]);
                acc[n * 4 + 2] = fmaf(xs, w.z, acc[n * 4 + 2]);
                acc[n * 4 + 3] = fmaf(xs, w.w, acc[n * 4 + 3]);
            }
        }
    }

    float h[JJ];
    #pragma unroll
    for (int n = 0; n < 4; ++n) {
        const float4 b4 = bs4[n];   // uniform
        #pragma unroll
        for (int k = 0; k < 4; ++k) {
            const float z = acc[n * 4 + k] + f4c(b4, k);
            h[n * 4 + k] = 1.0f / (1.0f + __expf(-z));
        }
    }

    // f(17)=f(18)=1; i=16..1: neg_i=(i==3||i==7)?1:1-h[i-1]; f(i)=h*f(i+1)+neg*f(i+2)
    float f1 = 1.0f, f2 = 1.0f;
    #pragma unroll
    for (int i = JJ; i >= 1; --i) {
        const float hj = h[i - 1];
        const float neg = (i == 3 || i == 7) ? 1.0f : (1.0f - hj);
        const float fi = fmaf(hj, f1, neg * f2);
        f2 = f1;
        f1 = fi;
    }

    const long long orow = wave_base + lane;
    if (full || orow < (long long)B) out[orow] = f1;
}

extern "C" void kernel_launch(void* const* d_in, const int* in_sizes, int n_in,
                              void* d_out, int out_size, void* d_ws, size_t ws_size,
                              hipStream_t stream) {
    const float* x  = (const float*)d_in[0];
    const float* Ws = (const float*)d_in[1];
    const float* bs = (const float*)d_in[2];
    float* out = (float*)d_out;

    const int B = in_sizes[0] / DD;
    const int grid = (B + BLOCK - 1) / BLOCK;

    net_circuit_kernel<<<grid, BLOCK, 0, stream>>>(x, Ws, bs, out, B);
}

// Round 8
// 43.429 us; speedup vs baseline: 2.1458x; 1.3432x over previous
//
#include <hip/hip_runtime.h>
#include <hip/hip_bf16.h>

#define BLOCK 256
#define DD 64
#define JJ 16

typedef __attribute__((ext_vector_type(8))) short short8;   // 8 bf16 (4 VGPRs)
typedef __attribute__((ext_vector_type(4))) float f32x4;    // MFMA acc

__device__ __forceinline__ short bfb(float f) {
    __hip_bfloat16 h = __float2bfloat16(f);
    short s; __builtin_memcpy(&s, &h, 2); return s;
}

// Skinny GEMM via MFMA: z(1M x 16) = x(1M x 64) . W(64 x 16), then
// sigmoid + 16-step circuit recurrence per row.
// Operand choice: D = A.B with A = W^T (m=j, k=d), B = x^T (k=d, n=row).
// C/D layout (m89-verified): col = lane&15 = row-in-tile, row = (lane>>4)*4+reg = j.
// A/B k-maps are permutation-invariant when both frags use the same e->k rule,
// so we use the simple contiguous rule k = kk*32 + (lane>>4)*8 + e.
// Epilogue: 4x f32x4 per lane -> wave-private LDS transpose (quad-swizzled,
// bank-optimal) -> each lane owns one row, does sigmoid+circuit, coalesced store.
// No __syncthreads anywhere (wave-local lgkmcnt only).
__global__ void net_circuit_kernel(
    const float* __restrict__ x, const float* __restrict__ Ws,
    const float* __restrict__ bs, float* __restrict__ out, int B)
{
    __shared__ float zl[4 * 64 * JJ];   // 4 waves x (64 rows x 16 j) f32 = 16 KB

    const int tid  = threadIdx.x;
    const int lane = tid & 63;
    const int wid  = tid >> 6;
    const int g    = lane >> 4;   // lane group 0..3
    const int r    = lane & 15;   // row-in-tile / j-owner index
    const long long wave_base = (long long)blockIdx.x * BLOCK + wid * 64;

    float* __restrict__ z = zl + wid * (64 * JJ);
    const float4* __restrict__ x4 = reinterpret_cast<const float4*>(x);

    // ---- A-frags from W^T: A[m=j=r][k=d], d = kk*32 + g*8 + e (4KB, L1-hot) ----
    short8 aw0, aw1;
    #pragma unroll
    for (int e = 0; e < 8; ++e) {
        const int d0 = g * 8 + e;
        const int d1 = 32 + g * 8 + e;
        aw0[e] = bfb(Ws[(r >> 2) * (DD * 4) + d0 * 4 + (r & 3)]);
        aw1[e] = bfb(Ws[(r >> 2) * (DD * 4) + d1 * 4 + (r & 3)]);
    }

    f32x4 acc[4];
    #pragma unroll
    for (int nt = 0; nt < 4; ++nt) acc[nt] = {0.f, 0.f, 0.f, 0.f};

    // ---- 4 row-tiles x (K=64 as 2 MFMAs) ----
    #pragma unroll
    for (int nt = 0; nt < 4; ++nt) {
        long long row = wave_base + nt * 16 + r;
        const long long rowc = (row < (long long)B) ? row : (long long)(B - 1);
        const float4* __restrict__ xr = x4 + rowc * (DD / 4);
        const float4 p0 = xr[g * 2];          // k = g*8 .. g*8+7      (kk=0)
        const float4 p1 = xr[g * 2 + 1];
        const float4 p2 = xr[8 + g * 2];      // k = 32 + g*8 ..       (kk=1)
        const float4 p3 = xr[8 + g * 2 + 1];

        short8 b0, b1;
        b0[0] = bfb(p0.x); b0[1] = bfb(p0.y); b0[2] = bfb(p0.z); b0[3] = bfb(p0.w);
        b0[4] = bfb(p1.x); b0[5] = bfb(p1.y); b0[6] = bfb(p1.z); b0[7] = bfb(p1.w);
        b1[0] = bfb(p2.x); b1[1] = bfb(p2.y); b1[2] = bfb(p2.z); b1[3] = bfb(p2.w);
        b1[4] = bfb(p3.x); b1[5] = bfb(p3.y); b1[6] = bfb(p3.z); b1[7] = bfb(p3.w);

        acc[nt] = __builtin_amdgcn_mfma_f32_16x16x32_bf16(aw0, b0, acc[nt], 0, 0, 0);
        acc[nt] = __builtin_amdgcn_mfma_f32_16x16x32_bf16(aw1, b1, acc[nt], 0, 0, 0);
    }

    // ---- transpose via wave-private LDS (quad-swizzled: slot = jb ^ (row&3)) ----
    // write: lane holds j-quad g of row nt*16+r -> banks spread evenly (depth-8 optimal)
    #pragma unroll
    for (int nt = 0; nt < 4; ++nt) {
        const int addr = (nt * 16 + r) * JJ + ((g ^ (r & 3)) * 4);
        *reinterpret_cast<f32x4*>(z + addr) = acc[nt];
    }
    asm volatile("s_waitcnt lgkmcnt(0)" ::: "memory");   // wave-local; no barrier

    // read: lane owns local row Ro = lane (= g*16 + r); Ro&3 == r&3
    float jv[JJ];
    #pragma unroll
    for (int jb = 0; jb < 4; ++jb) {
        const float4 q = *reinterpret_cast<const float4*>(
            z + lane * JJ + ((jb ^ (r & 3)) * 4));
        jv[jb * 4 + 0] = q.x; jv[jb * 4 + 1] = q.y;
        jv[jb * 4 + 2] = q.z; jv[jb * 4 + 3] = q.w;
    }

    // ---- bias + sigmoid (bias is uniform -> s_load) ----
    float h[JJ];
    #pragma unroll
    for (int j = 0; j < JJ; ++j) {
        const float zz = jv[j] + bs[j];
        h[j] = 1.0f / (1.0f + __expf(-zz));
    }

    // f(17)=f(18)=1; i=16..1: neg_i=(i==3||i==7)?1:1-h[i-1]; f(i)=h*f(i+1)+neg*f(i+2)
    float f1 = 1.0f, f2 = 1.0f;
    #pragma unroll
    for (int i = JJ; i >= 1; --i) {
        const float hj = h[i - 1];
        const float neg = (i == 3 || i == 7) ? 1.0f : (1.0f - hj);
        const float fi = fmaf(hj, f1, neg * f2);
        f2 = f1;
        f1 = fi;
    }

    const long long orow = wave_base + lane;   // 64 consecutive rows per wave
    if (orow < (long long)B) out[orow] = f1;
}

extern "C" void kernel_launch(void* const* d_in, const int* in_sizes, int n_in,
                              void* d_out, int out_size, void* d_ws, size_t ws_size,
                              hipStream_t stream) {
    const float* x  = (const float*)d_in[0];
    const float* Ws = (const float*)d_in[1];
    const float* bs = (const float*)d_in[2];
    float* out = (float*)d_out;

    const int B = in_sizes[0] / DD;
    const int grid = (B + BLOCK - 1) / BLOCK;

    net_circuit_kernel<<<grid, BLOCK, 0, stream>>>(x, Ws, bs, out, B);
}